// Round 1
// baseline (403.334 us; speedup 1.0000x reference)
//
#include <hip/hip_runtime.h>
#include <hip/hip_bf16.h>

// WeightedLoss: two-pass Gram-matrix loss on MI355X.
// Pass layout in d_ws:
//   [0]        Ob  bf16 8192x256  (4 MB)
//   [4194304]  Ln  bf16 8192x128  (2 MB)  (normalized labels)
//   [6291456]  sq  f32  8192
//   [6324224]  pos_sums f32 8192
//   [6356992]  neg_sums f32 8192
//   [6389760]  stats u32[3]: {smin_key, smax_key, d2max_key}

#define B_N 8192
#define NT  64      // 128-wide tiles per dim
#define TILE 128
#define BK 32

typedef __attribute__((ext_vector_type(8))) short bf16x8;
typedef __attribute__((ext_vector_type(4))) float f32x4;

typedef const __attribute__((address_space(1))) void g_void;
typedef __attribute__((address_space(3))) void l_void;

// order-preserving float<->uint for atomicMin/Max
__device__ __forceinline__ unsigned fenc(float f) {
    unsigned u = __float_as_uint(f);
    return (u & 0x80000000u) ? ~u : (u | 0x80000000u);
}
__device__ __forceinline__ float fdec(unsigned k) {
    unsigned u = (k & 0x80000000u) ? (k ^ 0x80000000u) : ~k;
    return __uint_as_float(u);
}

// ---------------------------------------------------------------- prep ----
__global__ __launch_bounds__(256) void prep_kernel(
    const float* __restrict__ outputs, const float* __restrict__ labels,
    __hip_bfloat16* __restrict__ Ob, __hip_bfloat16* __restrict__ Ln,
    float* __restrict__ sq, float* __restrict__ pos_sums,
    float* __restrict__ neg_sums, unsigned* __restrict__ stats) {
    int r = blockIdx.x, t = threadIdx.x;
    float v = outputs[(size_t)r * 256 + t];
    float s = v * v;
    #pragma unroll
    for (int m = 1; m < 64; m <<= 1) s += __shfl_xor(s, m);
    float lv = 0.f;
    if (t < 128) lv = labels[(size_t)r * 128 + t];
    float ls = lv * lv;
    #pragma unroll
    for (int m = 1; m < 64; m <<= 1) ls += __shfl_xor(ls, m);
    __shared__ float ws4[4];
    __shared__ float lsum2[2];
    if ((t & 63) == 0) ws4[t >> 6] = s;
    if (t < 128 && (t & 63) == 0) lsum2[t >> 6] = ls;
    __syncthreads();
    if (t == 0) sq[r] = ws4[0] + ws4[1] + ws4[2] + ws4[3];
    Ob[(size_t)r * 256 + t] = __float2bfloat16(v);
    if (t < 128) {
        float nrm = sqrtf(lsum2[0] + lsum2[1]) + 1e-12f;
        Ln[(size_t)r * 128 + t] = __float2bfloat16(lv / nrm);
    }
    if (t == 0) { pos_sums[r] = 0.f; neg_sums[r] = 0.f; }
    if (r == 0 && t == 0) {
        stats[0] = 0xFFFFFFFFu;  // smin key init (max key)
        stats[1] = 0u;           // smax key init (min key)
        stats[2] = 0u;           // d2max key init
    }
}

// ----------------------------------------------------- 128x128 Gram tile ----
// C_tile[m][n] = dot(X[rowBase+m], X[colBase+n]) over Kdim. bf16 MFMA 16x16x32.
// Block = 256 threads = 4 waves in 2x2; each wave computes 64x64 (4x4 frags).
__device__ __forceinline__ void gram_tile(
    const __hip_bfloat16* __restrict__ X, int Kdim, int rowBase, int colBase,
    short* As, short* Bs, f32x4 (&acc)[4][4], int tid) {
    int lane = tid & 63;
    int wid  = tid >> 6;
    int wm = (wid >> 1) * 64, wn = (wid & 1) * 64;
    int quad = lane >> 4, l15 = lane & 15;
    #pragma unroll
    for (int mi = 0; mi < 4; mi++)
        #pragma unroll
        for (int ni = 0; ni < 4; ni++) {
            f32x4 z = {0.f, 0.f, 0.f, 0.f};
            acc[mi][ni] = z;
        }
    for (int k0 = 0; k0 < Kdim; k0 += BK) {
        __syncthreads();   // previous iter's LDS reads done
        #pragma unroll
        for (int it = 0; it < 2; it++) {
            int e   = it * 2048 + tid * 8;   // element index into 128x32 tile
            int row = e >> 5, kk = e & 31;
            const __hip_bfloat16* ga = X + (size_t)(rowBase + row) * Kdim + k0 + kk;
            const __hip_bfloat16* gb = X + (size_t)(colBase + row) * Kdim + k0 + kk;
            __builtin_amdgcn_global_load_lds((g_void*)ga, (l_void*)&As[e], 16, 0, 0);
            __builtin_amdgcn_global_load_lds((g_void*)gb, (l_void*)&Bs[e], 16, 0, 0);
        }
        __syncthreads();   // staging drained (compiler emits vmcnt(0) before barrier)
        bf16x8 a[4], b[4];
        #pragma unroll
        for (int mi = 0; mi < 4; mi++)
            a[mi] = *(const bf16x8*)&As[(wm + mi * 16 + l15) * BK + quad * 8];
        #pragma unroll
        for (int ni = 0; ni < 4; ni++)
            b[ni] = *(const bf16x8*)&Bs[(wn + ni * 16 + l15) * BK + quad * 8];
        #pragma unroll
        for (int mi = 0; mi < 4; mi++)
            #pragma unroll
            for (int ni = 0; ni < 4; ni++)
                acc[mi][ni] = __builtin_amdgcn_mfma_f32_16x16x32_bf16(
                    a[mi], b[ni], acc[mi][ni], 0, 0, 0);
    }
}

// ---------------------------------------------------------------- stats ----
// Upper-triangular tiles only (symmetry): min/max of sim, max of d2.
__global__ __launch_bounds__(256) void stats_kernel(
    const __hip_bfloat16* __restrict__ Ln, const __hip_bfloat16* __restrict__ Ob,
    const float* __restrict__ sq, unsigned* __restrict__ stats) {
    int idx = blockIdx.x;
    int bi = 0, rem = idx;
    while (rem >= NT - bi) { rem -= NT - bi; bi++; }
    int bj = bi + rem;
    int rowBase = bi * TILE, colBase = bj * TILE;
    __shared__ __align__(16) short As[TILE * BK];
    __shared__ __align__(16) short Bs[TILE * BK];
    int tid = threadIdx.x;
    f32x4 acc[4][4];

    float lmin = 1e30f, lmax = -1e30f, dmax = 0.f;

    gram_tile(Ln, 128, rowBase, colBase, As, Bs, acc, tid);
    #pragma unroll
    for (int mi = 0; mi < 4; mi++)
        #pragma unroll
        for (int ni = 0; ni < 4; ni++)
            #pragma unroll
            for (int r = 0; r < 4; r++) {
                float s = acc[mi][ni][r];
                lmin = fminf(lmin, s);
                lmax = fmaxf(lmax, s);
            }

    gram_tile(Ob, 256, rowBase, colBase, As, Bs, acc, tid);
    int lane = tid & 63, wid = tid >> 6, quad = lane >> 4, l15 = lane & 15;
    int wm = (wid >> 1) * 64, wn = (wid & 1) * 64;
    float sqj[4];
    #pragma unroll
    for (int ni = 0; ni < 4; ni++) sqj[ni] = sq[colBase + wn + ni * 16 + l15];
    #pragma unroll
    for (int mi = 0; mi < 4; mi++)
        #pragma unroll
        for (int r = 0; r < 4; r++) {
            float sqi = sq[rowBase + wm + mi * 16 + quad * 4 + r];
            #pragma unroll
            for (int ni = 0; ni < 4; ni++) {
                float d2 = fmaxf(sqi + sqj[ni] - 2.f * acc[mi][ni][r], 0.f);
                dmax = fmaxf(dmax, d2);
            }
        }

    #pragma unroll
    for (int m = 1; m < 64; m <<= 1) {
        lmin = fminf(lmin, __shfl_xor(lmin, m));
        lmax = fmaxf(lmax, __shfl_xor(lmax, m));
        dmax = fmaxf(dmax, __shfl_xor(dmax, m));
    }
    __shared__ float red[3][4];
    if ((tid & 63) == 0) { red[0][wid] = lmin; red[1][wid] = lmax; red[2][wid] = dmax; }
    __syncthreads();
    if (tid == 0) {
        lmin = fminf(fminf(red[0][0], red[0][1]), fminf(red[0][2], red[0][3]));
        lmax = fmaxf(fmaxf(red[1][0], red[1][1]), fmaxf(red[1][2], red[1][3]));
        dmax = fmaxf(fmaxf(red[2][0], red[2][1]), fmaxf(red[2][2], red[2][3]));
        atomicMin(&stats[0], fenc(lmin));
        atomicMax(&stats[1], fenc(lmax));
        atomicMax(&stats[2], fenc(dmax));
    }
}

// ----------------------------------------------------------------- loss ----
__global__ __launch_bounds__(256) void loss_kernel(
    const __hip_bfloat16* __restrict__ Ln, const __hip_bfloat16* __restrict__ Ob,
    const float* __restrict__ sq, const unsigned* __restrict__ stats,
    float* __restrict__ pos_sums, float* __restrict__ neg_sums) {
    int bi = blockIdx.y, bj = blockIdx.x;
    int rowBase = bi * TILE, colBase = bj * TILE;
    __shared__ __align__(16) short As[TILE * BK];
    __shared__ __align__(16) short Bs[TILE * BK];
    __shared__ float rP[TILE][2];
    __shared__ float rN[TILE][2];
    int tid = threadIdx.x;
    f32x4 accS[4][4], accG[4][4];

    gram_tile(Ln, 128, rowBase, colBase, As, Bs, accS, tid);
    gram_tile(Ob, 256, rowBase, colBase, As, Bs, accG, tid);

    float smin = fdec(stats[0]);
    float smax = fdec(stats[1]);
    float d2max = fdec(stats[2]);
    float invr  = 1.f / (smax - smin);
    float invem = rsqrtf(d2max);

    int lane = tid & 63, wid = tid >> 6, quad = lane >> 4, l15 = lane & 15;
    int wm = (wid >> 1) * 64, wn = (wid & 1) * 64;
    float sqj[4];
    #pragma unroll
    for (int ni = 0; ni < 4; ni++) sqj[ni] = sq[colBase + wn + ni * 16 + l15];

    #pragma unroll
    for (int mi = 0; mi < 4; mi++)
        #pragma unroll
        for (int r = 0; r < 4; r++) {
            float sqi = sq[rowBase + wm + mi * 16 + quad * 4 + r];
            float psum = 0.f, nsum = 0.f;
            #pragma unroll
            for (int ni = 0; ni < 4; ni++) {
                float s  = accS[mi][ni][r];
                float g  = accG[mi][ni][r];
                float sn = (s - smin) * invr;
                float d2 = fmaxf(sqi + sqj[ni] - 2.f * g, 0.f);
                float eud = (d2 > 0.f) ? sqrtf(d2) * invem : 0.f;
                float dist = eud + sn;
                bool pos = sn > 0.5f;   // TAU
                psum += pos ? __expf(dist) : 0.f;
                nsum += pos ? 0.f : __expf(1.0f - dist);  // MAG = 1
            }
            // sum over the 16 columns this lane-group covers
            #pragma unroll
            for (int m = 1; m < 16; m <<= 1) {
                psum += __shfl_xor(psum, m);
                nsum += __shfl_xor(nsum, m);
            }
            if (l15 == 0) {
                int rr = wm + mi * 16 + quad * 4 + r;
                rP[rr][wid & 1] = psum;
                rN[rr][wid & 1] = nsum;
            }
        }
    __syncthreads();
    if (tid < TILE) {
        atomicAdd(&pos_sums[rowBase + tid], rP[tid][0] + rP[tid][1]);
        atomicAdd(&neg_sums[rowBase + tid], rN[tid][0] + rN[tid][1]);
    }
}

// ------------------------------------------------------------- finalize ----
__global__ __launch_bounds__(256) void finalize_kernel(
    const float* __restrict__ pos_sums, const float* __restrict__ neg_sums,
    float* __restrict__ out) {
    int t = threadIdx.x;
    float acc = 0.f;
    for (int i = t; i < B_N; i += 256) {
        float p = pos_sums[i], n = neg_sums[i];
        float pl = fmaxf(logf(p), 0.f);
        float nl = (n > 0.f) ? fmaxf(logf(n), 0.f) : 0.f;
        acc += pl + nl;
    }
    #pragma unroll
    for (int m = 1; m < 64; m <<= 1) acc += __shfl_xor(acc, m);
    __shared__ float w4[4];
    if ((t & 63) == 0) w4[t >> 6] = acc;
    __syncthreads();
    if (t == 0) out[0] = (w4[0] + w4[1] + w4[2] + w4[3]) / (float)B_N;
}

// ------------------------------------------------------------------ entry ----
extern "C" void kernel_launch(void* const* d_in, const int* in_sizes, int n_in,
                              void* d_out, int out_size, void* d_ws, size_t ws_size,
                              hipStream_t stream) {
    const float* outputs = (const float*)d_in[0];
    const float* labels  = (const float*)d_in[1];
    float* out = (float*)d_out;
    char* ws = (char*)d_ws;
    __hip_bfloat16* Ob = (__hip_bfloat16*)(ws);
    __hip_bfloat16* Ln = (__hip_bfloat16*)(ws + 4194304);
    float* sq          = (float*)(ws + 6291456);
    float* pos_sums    = (float*)(ws + 6324224);
    float* neg_sums    = (float*)(ws + 6356992);
    unsigned* stats    = (unsigned*)(ws + 6389760);

    prep_kernel<<<B_N, 256, 0, stream>>>(outputs, labels, Ob, Ln, sq,
                                         pos_sums, neg_sums, stats);
    stats_kernel<<<NT * (NT + 1) / 2, 256, 0, stream>>>(Ln, Ob, sq, stats);
    loss_kernel<<<dim3(NT, NT), 256, 0, stream>>>(Ln, Ob, sq, stats,
                                                  pos_sums, neg_sums);
    finalize_kernel<<<1, 256, 0, stream>>>(pos_sums, neg_sums, out);
}

// Round 2
// 326.324 us; speedup vs baseline: 1.2360x; 1.2360x over previous
//
#include <hip/hip_runtime.h>
#include <hip/hip_bf16.h>

// WeightedLoss: two-pass Gram-matrix loss on MI355X.
// Round 2: barrier-free direct-from-global MFMA fragments (no LDS staging),
// upper-triangular loss grid with row+column accumulation (symmetry).
// ws layout:
//   [0]        Ob  bf16 8192x256  (4 MB)
//   [4194304]  Ln  bf16 8192x128  (2 MB)  (normalized labels)
//   [6291456]  sq  f32  8192
//   [6324224]  pos_sums f32 8192
//   [6356992]  neg_sums f32 8192
//   [6389760]  stats u32[3]: {smin_key, smax_key, d2max_key}

#define B_N 8192
#define NT   64      // 128-wide tiles per dim
#define TILE 128
#define NTRI (NT * (NT + 1) / 2)   // 2080 upper-tri tiles

typedef __attribute__((ext_vector_type(8))) short bf16x8;
typedef __attribute__((ext_vector_type(4))) float f32x4;

// order-preserving float<->uint for atomicMin/Max
__device__ __forceinline__ unsigned fenc(float f) {
    unsigned u = __float_as_uint(f);
    return (u & 0x80000000u) ? ~u : (u | 0x80000000u);
}
__device__ __forceinline__ float fdec(unsigned k) {
    unsigned u = (k & 0x80000000u) ? (k ^ 0x80000000u) : ~k;
    return __uint_as_float(u);
}

__device__ __forceinline__ void tri_decode(int idx, int& bi, int& bj) {
    int i = 0, rem = idx;
    while (rem >= NT - i) { rem -= NT - i; i++; }
    bi = i; bj = i + rem;
}

// ---------------------------------------------------------------- prep ----
__global__ __launch_bounds__(256) void prep_kernel(
    const float* __restrict__ outputs, const float* __restrict__ labels,
    __hip_bfloat16* __restrict__ Ob, __hip_bfloat16* __restrict__ Ln,
    float* __restrict__ sq, float* __restrict__ pos_sums,
    float* __restrict__ neg_sums, unsigned* __restrict__ stats) {
    int r = blockIdx.x, t = threadIdx.x;
    float v = outputs[(size_t)r * 256 + t];
    float s = v * v;
    #pragma unroll
    for (int m = 1; m < 64; m <<= 1) s += __shfl_xor(s, m);
    float lv = 0.f;
    if (t < 128) lv = labels[(size_t)r * 128 + t];
    float ls = lv * lv;
    #pragma unroll
    for (int m = 1; m < 64; m <<= 1) ls += __shfl_xor(ls, m);
    __shared__ float ws4[4];
    __shared__ float lsum2[2];
    if ((t & 63) == 0) ws4[t >> 6] = s;
    if (t < 128 && (t & 63) == 0) lsum2[t >> 6] = ls;
    __syncthreads();
    if (t == 0) sq[r] = ws4[0] + ws4[1] + ws4[2] + ws4[3];
    Ob[(size_t)r * 256 + t] = __float2bfloat16(v);
    if (t < 128) {
        float nrm = sqrtf(lsum2[0] + lsum2[1]) + 1e-12f;
        Ln[(size_t)r * 128 + t] = __float2bfloat16(lv / nrm);
    }
    if (t == 0) { pos_sums[r] = 0.f; neg_sums[r] = 0.f; }
    if (r == 0 && t == 0) {
        stats[0] = 0xFFFFFFFFu;  // smin key init (max key)
        stats[1] = 0u;           // smax key init (min key)
        stats[2] = 0u;           // d2max key init
    }
}

// --------------------------------------------- direct-global 64x64 gram ----
// Wave computes a 64x64 tile of X X^T via 16x16x32 bf16 MFMA, loading A/B
// fragments straight from row-major global memory (16 B contiguous per lane).
// No LDS, no barriers — compiler software-pipelines the unrolled k-loop.
template<int KDIM>
__device__ __forceinline__ void gram_direct(
    const __hip_bfloat16* __restrict__ X, int rowBase, int colBase,
    int l15, int quad, f32x4 (&acc)[4][4]) {
    const bf16x8* pa[4];
    const bf16x8* pb[4];
    #pragma unroll
    for (int mi = 0; mi < 4; mi++)
        pa[mi] = (const bf16x8*)(X + (size_t)(rowBase + mi * 16 + l15) * KDIM + quad * 8);
    #pragma unroll
    for (int ni = 0; ni < 4; ni++)
        pb[ni] = (const bf16x8*)(X + (size_t)(colBase + ni * 16 + l15) * KDIM + quad * 8);
    #pragma unroll
    for (int mi = 0; mi < 4; mi++)
        #pragma unroll
        for (int ni = 0; ni < 4; ni++) {
            f32x4 z = {0.f, 0.f, 0.f, 0.f};
            acc[mi][ni] = z;
        }
    #pragma unroll
    for (int k0 = 0; k0 < KDIM; k0 += 32) {
        bf16x8 a[4], b[4];
        #pragma unroll
        for (int mi = 0; mi < 4; mi++) a[mi] = pa[mi][k0 >> 3];
        #pragma unroll
        for (int ni = 0; ni < 4; ni++) b[ni] = pb[ni][k0 >> 3];
        #pragma unroll
        for (int mi = 0; mi < 4; mi++)
            #pragma unroll
            for (int ni = 0; ni < 4; ni++)
                acc[mi][ni] = __builtin_amdgcn_mfma_f32_16x16x32_bf16(
                    a[mi], b[ni], acc[mi][ni], 0, 0, 0);
    }
}

// ---------------------------------------------------------------- stats ----
// Upper-triangular tiles (symmetry): min/max of sim, max of d2.
__global__ __launch_bounds__(256, 2) void stats_kernel(
    const __hip_bfloat16* __restrict__ Ln, const __hip_bfloat16* __restrict__ Ob,
    const float* __restrict__ sq, unsigned* __restrict__ stats) {
    int bi, bj;
    tri_decode(blockIdx.x, bi, bj);
    int tid = threadIdx.x, lane = tid & 63, wid = tid >> 6;
    int wm = (wid >> 1) * 64, wn = (wid & 1) * 64;
    int l15 = lane & 15, quad = lane >> 4;
    int rowBase = bi * TILE + wm, colBase = bj * TILE + wn;
    f32x4 acc[4][4];

    float lmin = 1e30f, lmax = -1e30f, dmax = 0.f;

    gram_direct<128>(Ln, rowBase, colBase, l15, quad, acc);
    #pragma unroll
    for (int mi = 0; mi < 4; mi++)
        #pragma unroll
        for (int ni = 0; ni < 4; ni++)
            #pragma unroll
            for (int r = 0; r < 4; r++) {
                float s = acc[mi][ni][r];
                lmin = fminf(lmin, s);
                lmax = fmaxf(lmax, s);
            }

    gram_direct<256>(Ob, rowBase, colBase, l15, quad, acc);
    float sqj[4];
    #pragma unroll
    for (int ni = 0; ni < 4; ni++) sqj[ni] = sq[colBase + ni * 16 + l15];
    #pragma unroll
    for (int mi = 0; mi < 4; mi++) {
        f32x4 sqi = *(const f32x4*)&sq[rowBase + mi * 16 + quad * 4];
        #pragma unroll
        for (int r = 0; r < 4; r++)
            #pragma unroll
            for (int ni = 0; ni < 4; ni++) {
                float d2 = fmaxf(sqi[r] + sqj[ni] - 2.f * acc[mi][ni][r], 0.f);
                dmax = fmaxf(dmax, d2);
            }
    }

    #pragma unroll
    for (int m = 1; m < 64; m <<= 1) {
        lmin = fminf(lmin, __shfl_xor(lmin, m));
        lmax = fmaxf(lmax, __shfl_xor(lmax, m));
        dmax = fmaxf(dmax, __shfl_xor(dmax, m));
    }
    __shared__ float red[3][4];
    if ((tid & 63) == 0) { red[0][wid] = lmin; red[1][wid] = lmax; red[2][wid] = dmax; }
    __syncthreads();
    if (tid == 0) {
        lmin = fminf(fminf(red[0][0], red[0][1]), fminf(red[0][2], red[0][3]));
        lmax = fmaxf(fmaxf(red[1][0], red[1][1]), fmaxf(red[1][2], red[1][3]));
        dmax = fmaxf(fmaxf(red[2][0], red[2][1]), fmaxf(red[2][2], red[2][3]));
        atomicMin(&stats[0], fenc(lmin));
        atomicMax(&stats[1], fenc(lmax));
        atomicMax(&stats[2], fenc(dmax));
    }
}

// ----------------------------------------------------------------- loss ----
// Upper-triangular grid; each tile contributes row-side sums (rows of bi)
// and, if off-diagonal, column-side sums (rows of bj, by symmetry).
__global__ __launch_bounds__(256, 2) void loss_kernel(
    const __hip_bfloat16* __restrict__ Ln, const __hip_bfloat16* __restrict__ Ob,
    const float* __restrict__ sq, const unsigned* __restrict__ stats,
    float* __restrict__ pos_sums, float* __restrict__ neg_sums) {
    int bi, bj;
    tri_decode(blockIdx.x, bi, bj);
    int tid = threadIdx.x, lane = tid & 63, wid = tid >> 6;
    int wm = (wid >> 1) * 64, wn = (wid & 1) * 64;
    int l15 = lane & 15, quad = lane >> 4;
    int rowBase = bi * TILE + wm, colBase = bj * TILE + wn;

    f32x4 accS[4][4], accG[4][4];
    gram_direct<128>(Ln, rowBase, colBase, l15, quad, accS);
    gram_direct<256>(Ob, rowBase, colBase, l15, quad, accG);

    float smin = fdec(stats[0]);
    float smax = fdec(stats[1]);
    float d2max = fdec(stats[2]);
    float invr = 1.f / (smax - smin);
    float invem = rsqrtf(d2max);

    __shared__ float rP[TILE][2], rN[TILE][2];
    __shared__ float cP[TILE][2], cN[TILE][2];

    float sqj[4];
    #pragma unroll
    for (int ni = 0; ni < 4; ni++) sqj[ni] = sq[colBase + ni * 16 + l15];
    float cpsum[4] = {0.f, 0.f, 0.f, 0.f};
    float cnsum[4] = {0.f, 0.f, 0.f, 0.f};

    #pragma unroll
    for (int mi = 0; mi < 4; mi++) {
        f32x4 sqi = *(const f32x4*)&sq[rowBase + mi * 16 + quad * 4];
        #pragma unroll
        for (int r = 0; r < 4; r++) {
            float psum = 0.f, nsum = 0.f;
            #pragma unroll
            for (int ni = 0; ni < 4; ni++) {
                float s = accS[mi][ni][r];
                float g = accG[mi][ni][r];
                float sn = (s - smin) * invr;
                float d2 = fmaxf(sqi[r] + sqj[ni] - 2.f * g, 0.f);
                float eud = (d2 > 0.f) ? sqrtf(d2) * invem : 0.f;
                float dist = eud + sn;
                bool pos = sn > 0.5f;   // TAU
                float pv = pos ? __expf(dist) : 0.f;
                float nv = pos ? 0.f : __expf(1.0f - dist);   // MAG = 1
                psum += pv;  nsum += nv;
                cpsum[ni] += pv;  cnsum[ni] += nv;
            }
            #pragma unroll
            for (int m = 1; m < 16; m <<= 1) {
                psum += __shfl_xor(psum, m);
                nsum += __shfl_xor(nsum, m);
            }
            if (l15 == 0) {
                int rr = wm + mi * 16 + quad * 4 + r;
                rP[rr][wid & 1] = psum;
                rN[rr][wid & 1] = nsum;
            }
        }
    }
    // column-side: sum over the 4 quads (lane bits 4,5)
    #pragma unroll
    for (int ni = 0; ni < 4; ni++) {
        #pragma unroll
        for (int m = 16; m < 64; m <<= 1) {
            cpsum[ni] += __shfl_xor(cpsum[ni], m);
            cnsum[ni] += __shfl_xor(cnsum[ni], m);
        }
        if (quad == 0) {
            int cc = wn + ni * 16 + l15;
            cP[cc][wid >> 1] = cpsum[ni];
            cN[cc][wid >> 1] = cnsum[ni];
        }
    }
    __syncthreads();
    if (tid < TILE) {
        atomicAdd(&pos_sums[bi * TILE + tid], rP[tid][0] + rP[tid][1]);
        atomicAdd(&neg_sums[bi * TILE + tid], rN[tid][0] + rN[tid][1]);
        if (bi != bj) {
            atomicAdd(&pos_sums[bj * TILE + tid], cP[tid][0] + cP[tid][1]);
            atomicAdd(&neg_sums[bj * TILE + tid], cN[tid][0] + cN[tid][1]);
        }
    }
}

// ------------------------------------------------------------- finalize ----
__global__ __launch_bounds__(256) void finalize_kernel(
    const float* __restrict__ pos_sums, const float* __restrict__ neg_sums,
    float* __restrict__ out) {
    int t = threadIdx.x;
    float acc = 0.f;
    for (int i = t; i < B_N; i += 256) {
        float p = pos_sums[i], n = neg_sums[i];
        float pl = fmaxf(logf(p), 0.f);
        float nl = (n > 0.f) ? fmaxf(logf(n), 0.f) : 0.f;
        acc += pl + nl;
    }
    #pragma unroll
    for (int m = 1; m < 64; m <<= 1) acc += __shfl_xor(acc, m);
    __shared__ float w4[4];
    if ((t & 63) == 0) w4[t >> 6] = acc;
    __syncthreads();
    if (t == 0) out[0] = (w4[0] + w4[1] + w4[2] + w4[3]) / (float)B_N;
}

// ------------------------------------------------------------------ entry ----
extern "C" void kernel_launch(void* const* d_in, const int* in_sizes, int n_in,
                              void* d_out, int out_size, void* d_ws, size_t ws_size,
                              hipStream_t stream) {
    const float* outputs = (const float*)d_in[0];
    const float* labels  = (const float*)d_in[1];
    float* out = (float*)d_out;
    char* ws = (char*)d_ws;
    __hip_bfloat16* Ob = (__hip_bfloat16*)(ws);
    __hip_bfloat16* Ln = (__hip_bfloat16*)(ws + 4194304);
    float* sq          = (float*)(ws + 6291456);
    float* pos_sums    = (float*)(ws + 6324224);
    float* neg_sums    = (float*)(ws + 6356992);
    unsigned* stats    = (unsigned*)(ws + 6389760);

    prep_kernel<<<B_N, 256, 0, stream>>>(outputs, labels, Ob, Ln, sq,
                                         pos_sums, neg_sums, stats);
    stats_kernel<<<NTRI, 256, 0, stream>>>(Ln, Ob, sq, stats);
    loss_kernel<<<NTRI, 256, 0, stream>>>(Ln, Ob, sq, stats,
                                          pos_sums, neg_sums);
    finalize_kernel<<<1, 256, 0, stream>>>(pos_sums, neg_sums, out);
}